// Round 18
// baseline (1633.030 us; speedup 1.0000x reference)
//
#include <hip/hip_runtime.h>
#include <hip/hip_bf16.h>
#include <stdint.h>

// DbrxExpertGLU: down = (silu(x@w1^T) * (x@v1^T)) @ w2
// T=4096, H=4096, F=14336. fp32 in/out; bf16 MFMA compute.
// R18: 2-blocks/CU redesign. BK=32, [rows][32]-elem LDS panels (contiguous
// 1KB wave reads -> conflict-free, NO swizzle, linear staging), waves 4x2,
// per-wave acc 64 regs -> ~116 VGPR -> __launch_bounds__(512,4) -> 4 waves/SIMD.
// LDS 56KB/block: A dbuf 2x16K + {WV|B} tribuf 3x8K. Counted gate vmcnt(1),
// 1 barrier/tile, 2-tile lead on the streamed operand.
#define TOKENS 4096
#define HIDDEN 4096
#define FFN    14336

typedef __attribute__((ext_vector_type(8))) short bf16x8;
typedef __attribute__((ext_vector_type(4))) float f32x4;
typedef __attribute__((ext_vector_type(8))) unsigned short u16x8;

typedef __attribute__((address_space(3))) void lds_void_t;
typedef const __attribute__((address_space(1))) void gbl_void_t;

static __device__ __forceinline__ unsigned short f2b(float f) {
  union { float f; unsigned int u; } v; v.f = f;
  unsigned int u = v.u;
  return (unsigned short)((u + 0x7FFFu + ((u >> 16) & 1u)) >> 16);  // RNE
}

// ---------------- fp32 -> bf16 convert ----------------
__global__ void cvt_kernel(const float* __restrict__ in, unsigned short* __restrict__ out, long n) {
  long idx = (long)blockIdx.x * blockDim.x + threadIdx.x;
  long stride = (long)gridDim.x * blockDim.x;
  for (long i = idx * 4; i < n; i += stride * 4) {
    const float4 v = *reinterpret_cast<const float4*>(in + i);
    ushort4 o;
    o.x = f2b(v.x); o.y = f2b(v.y); o.z = f2b(v.z); o.w = f2b(v.w);
    *reinterpret_cast<ushort4*>(out + i) = o;
  }
}

// ------- w2 [F][H] fp32 -> w2t [H][F] bf16 -------
__global__ void transpose_cvt_kernel(const float* __restrict__ in, unsigned short* __restrict__ out) {
  __shared__ float tile[64][65];
  const int f0 = blockIdx.x * 64;
  const int h0 = blockIdx.y * 64;
  const int t = threadIdx.x;
  const int rcol = (t & 15) * 4;
  const int rrow = t >> 4;
#pragma unroll
  for (int it = 0; it < 4; ++it) {
    int r = rrow + it * 16;
    const float4 v = *reinterpret_cast<const float4*>(in + (long)(f0 + r) * HIDDEN + h0 + rcol);
    tile[r][rcol] = v.x; tile[r][rcol + 1] = v.y; tile[r][rcol + 2] = v.z; tile[r][rcol + 3] = v.w;
  }
  __syncthreads();
  const int wrow = t >> 2;
  const int wc = (t & 3) * 16;
  u16x8 lo, hi;
#pragma unroll
  for (int j = 0; j < 8; ++j) lo[j] = f2b(tile[wc + j][wrow]);
#pragma unroll
  for (int j = 0; j < 8; ++j) hi[j] = f2b(tile[wc + 8 + j][wrow]);
  u16x8* dst = reinterpret_cast<u16x8*>(out + (long)(h0 + wrow) * FFN + f0 + wc);
  dst[0] = lo; dst[1] = hi;
}

#define MFMA16(a, b, c) __builtin_amdgcn_mfma_f32_16x16x32_bf16((a), (b), (c), 0, 0, 0)
#define SBAR()  __builtin_amdgcn_s_barrier()

static __device__ __forceinline__ int xcd_chunk(int bid, int nwg) {
  return (bid & 7) * (nwg >> 3) + (bid >> 3);
}

// ============ gateup: block 256(T) x 64(F), BK=32, 8 waves (4x2), 2 blocks/CU ============
// LDS 56KB: A dbuf @0,@16K ([256][32] elems each) | WV slot s @32K+s*8K (W 4K, V 4K).
__global__ __launch_bounds__(512, 4)
void gateup256c_kernel(const unsigned short* __restrict__ X,
                       const unsigned short* __restrict__ W1,
                       const unsigned short* __restrict__ V1,
                       unsigned short* __restrict__ Inter,
                       int bnBase, int nwg) {
  __shared__ unsigned short sh[28672];  // 56 KB
  const int tid = threadIdx.x, lane = tid & 63, wid = tid >> 6;
  const int wm = wid >> 1, wn = wid & 1;
  const int swz = xcd_chunk(blockIdx.x, nwg);
  const int bm = swz & 15;              // T-tile fastest
  const int bn = bnBase + (swz >> 4);   // 64-col F-tile
  const int l15 = lane & 15;
  const int kb = (lane >> 4) * 16;      // byte col within 64B row

  const unsigned short* Ap = X  + (long)(bm * 256) * HIDDEN;
  const unsigned short* Wp = W1 + (long)(bn * 64) * HIDDEN;
  const unsigned short* Vp = V1 + (long)(bn * 64) * HIDDEN;

  f32x4 accg[4][2] = {};
  f32x4 accu[4][2] = {};

  auto STA = [&](int bufA, int t) {  // [256][32], 16KB, 2 gloads/thread
    const unsigned short* src = Ap + (long)(tid >> 2) * HIDDEN + t * 32 + (tid & 3) * 8;
    unsigned short* dst = sh + bufA * 8192 + tid * 8;
    __builtin_amdgcn_global_load_lds((gbl_void_t*)src, (lds_void_t*)dst, 16, 0, 0);
    __builtin_amdgcn_global_load_lds((gbl_void_t*)(src + 128L * HIDDEN), (lds_void_t*)(dst + 4096), 16, 0, 0);
  };
  auto STWV = [&](int s3, int t) {   // W 4KB by waves 0-3, V 4KB by waves 4-7; 1 gload/thread
    if (tid < 256) {
      const unsigned short* src = Wp + (long)(tid >> 2) * HIDDEN + t * 32 + (tid & 3) * 8;
      unsigned short* dst = sh + 16384 + s3 * 4096 + tid * 8;
      __builtin_amdgcn_global_load_lds((gbl_void_t*)src, (lds_void_t*)dst, 16, 0, 0);
    } else {
      const int t2 = tid - 256;
      const unsigned short* src = Vp + (long)(t2 >> 2) * HIDDEN + t * 32 + (t2 & 3) * 8;
      unsigned short* dst = sh + 16384 + s3 * 4096 + 2048 + t2 * 8;
      __builtin_amdgcn_global_load_lds((gbl_void_t*)src, (lds_void_t*)dst, 16, 0, 0);
    }
  };
  auto LDA4 = [&](bf16x8* a, int bufA) {
    const char* base = (const char*)sh + bufA * 16384 + (wm * 64 + l15) * 64 + kb;
#pragma unroll
    for (int m = 0; m < 4; ++m) a[m] = *(const bf16x8*)(base + m * 1024);
  };
  auto LDW2 = [&](bf16x8* w, int s3) {
    const char* base = (const char*)sh + 32768 + s3 * 8192 + (wn * 32 + l15) * 64 + kb;
    w[0] = *(const bf16x8*)(base);
    w[1] = *(const bf16x8*)(base + 1024);
  };
  auto LDV2 = [&](bf16x8* v, int s3) {
    const char* base = (const char*)sh + 32768 + s3 * 8192 + 4096 + (wn * 32 + l15) * 64 + kb;
    v[0] = *(const bf16x8*)(base);
    v[1] = *(const bf16x8*)(base + 1024);
  };

  // prologue (ledger order): WV(0)->s0 (1); A(0)->buf0 (2); WV(1)->s1 (1)
  STWV(0, 0);
  STA(0, 0);
  STWV(1, 1);

  bf16x8 a[4], w[2], v[2];
  const int NT = HIDDEN / 32;  // 128
  for (int t = 0; t < NT; ++t) {
    const int curA = t & 1, nxtA = curA ^ 1;
    const int s3 = t % 3, s3w = (t + 2) % 3;
    asm volatile("s_waitcnt lgkmcnt(0)" ::: "memory");
    // gate: keep newest 1 (WV(t+1)); drains A(t), WV(t)
    if (t + 1 < NT) { asm volatile("s_waitcnt vmcnt(1)" ::: "memory"); }
    else            { asm volatile("s_waitcnt vmcnt(0)" ::: "memory"); }
    SBAR();
    // post-barrier staging (ledger order): A(t+1) first (2), then WV(t+2) (1)
    if (t + 1 < NT) STA(nxtA, t + 1);
    if (t + 2 < NT) STWV(s3w, t + 2);
    LDA4(a, curA); LDW2(w, s3); LDV2(v, s3);
    __builtin_amdgcn_s_setprio(1);
#pragma unroll
    for (int m = 0; m < 4; ++m) {
      accg[m][0] = MFMA16(a[m], w[0], accg[m][0]);
      accg[m][1] = MFMA16(a[m], w[1], accg[m][1]);
    }
#pragma unroll
    for (int m = 0; m < 4; ++m) {
      accu[m][0] = MFMA16(a[m], v[0], accu[m][0]);
      accu[m][1] = MFMA16(a[m], v[1], accu[m][1]);
    }
    __builtin_amdgcn_s_setprio(0);
  }
  // epilogue: silu(g)*u -> bf16. C/D map: col=lane&15, row=(lane>>4)*4+r (m89)
  const int r0 = (lane >> 4) * 4;
#pragma unroll
  for (int m = 0; m < 4; ++m)
#pragma unroll
    for (int n = 0; n < 2; ++n)
#pragma unroll
      for (int r = 0; r < 4; ++r) {
        const float g = accg[m][n][r];
        const float u = accu[m][n][r];
        const float s = g / (1.0f + __expf(-g));
        const int row = bm * 256 + wm * 64 + m * 16 + r0 + r;
        const int col = bn * 64 + wn * 32 + n * 16 + l15;
        Inter[(long)row * FFN + col] = f2b(s * u);
      }
}

// ============ down: block 256(T) x 128(H), BK=32, 8 waves (4x2), 2 blocks/CU ============
// LDS 56KB: A dbuf @0,@16K ([256][32]) | B slot s @32K+s*8K ([128][32]).
__global__ __launch_bounds__(512, 4)
void down256c_kernel(const unsigned short* __restrict__ Inter,
                     const unsigned short* __restrict__ W2t,
                     float* __restrict__ Out) {
  __shared__ unsigned short sh[28672];  // 56 KB
  const int tid = threadIdx.x, lane = tid & 63, wid = tid >> 6;
  const int wm = wid >> 1, wn = wid & 1;
  const int swz = xcd_chunk(blockIdx.x, (TOKENS / 256) * (HIDDEN / 128));  // 512
  const int bm = swz & 15;
  const int bn = swz >> 4;
  const int l15 = lane & 15;
  const int kb = (lane >> 4) * 16;

  const unsigned short* Ap = Inter + (long)(bm * 256) * FFN;
  const unsigned short* Bp = W2t + (long)(bn * 128) * FFN;

  f32x4 acc[4][4] = {};

  auto STA = [&](int bufA, int t) {  // 16KB, 2 gloads/thread
    const unsigned short* src = Ap + (long)(tid >> 2) * FFN + t * 32 + (tid & 3) * 8;
    unsigned short* dst = sh + bufA * 8192 + tid * 8;
    __builtin_amdgcn_global_load_lds((gbl_void_t*)src, (lds_void_t*)dst, 16, 0, 0);
    __builtin_amdgcn_global_load_lds((gbl_void_t*)(src + 128L * FFN), (lds_void_t*)(dst + 4096), 16, 0, 0);
  };
  auto STB = [&](int s3, int t) {    // [128][32] 8KB, 1 gload/thread
    const unsigned short* src = Bp + (long)(tid >> 2) * FFN + t * 32 + (tid & 3) * 8;
    unsigned short* dst = sh + 16384 + s3 * 4096 + tid * 8;
    __builtin_amdgcn_global_load_lds((gbl_void_t*)src, (lds_void_t*)dst, 16, 0, 0);
  };
  auto LDA4 = [&](bf16x8* a, int bufA) {
    const char* base = (const char*)sh + bufA * 16384 + (wm * 64 + l15) * 64 + kb;
#pragma unroll
    for (int m = 0; m < 4; ++m) a[m] = *(const bf16x8*)(base + m * 1024);
  };
  auto LDB4 = [&](bf16x8* b, int s3) {
    const char* base = (const char*)sh + 32768 + s3 * 8192 + (wn * 64 + l15) * 64 + kb;
#pragma unroll
    for (int n = 0; n < 4; ++n) b[n] = *(const bf16x8*)(base + n * 1024);
  };

  // prologue: B(0)->s0 (1); A(0)->buf0 (2); B(1)->s1 (1)
  STB(0, 0);
  STA(0, 0);
  STB(1, 1);

  bf16x8 a[4], b[4];
  const int NT = FFN / 32;  // 448
  for (int t = 0; t < NT; ++t) {
    const int curA = t & 1, nxtA = curA ^ 1;
    const int s3 = t % 3, s3w = (t + 2) % 3;
    asm volatile("s_waitcnt lgkmcnt(0)" ::: "memory");
    if (t + 1 < NT) { asm volatile("s_waitcnt vmcnt(1)" ::: "memory"); }
    else            { asm volatile("s_waitcnt vmcnt(0)" ::: "memory"); }
    SBAR();
    if (t + 1 < NT) STA(nxtA, t + 1);
    if (t + 2 < NT) STB(s3w, t + 2);
    LDA4(a, curA); LDB4(b, s3);
    __builtin_amdgcn_s_setprio(1);
#pragma unroll
    for (int m = 0; m < 4; ++m) {
      acc[m][0] = MFMA16(a[m], b[0], acc[m][0]);
      acc[m][1] = MFMA16(a[m], b[1], acc[m][1]);
    }
#pragma unroll
    for (int m = 0; m < 4; ++m) {
      acc[m][2] = MFMA16(a[m], b[2], acc[m][2]);
      acc[m][3] = MFMA16(a[m], b[3], acc[m][3]);
    }
    __builtin_amdgcn_s_setprio(0);
  }
  const int r0 = (lane >> 4) * 4;
#pragma unroll
  for (int m = 0; m < 4; ++m)
#pragma unroll
    for (int n = 0; n < 4; ++n)
#pragma unroll
      for (int r = 0; r < 4; ++r) {
        const int row = bm * 256 + wm * 64 + m * 16 + r0 + r;
        const int col = bn * 128 + wn * 64 + n * 16 + l15;
        Out[(long)row * HIDDEN + col] = acc[m][n][r];
      }
}

// ---- fallback down (round-2 verified) when ws lacks w2t space ----
__device__ __forceinline__ void stage_tile_128(const unsigned short* __restrict__ g, long ldk,
                                               unsigned short* lds, int wave, int lane) {
#pragma unroll
  for (int it = 0; it < 2; ++it) {
    const int row = (it * 4 + wave) * 16 + (lane >> 2);
    const int kcol = (lane & 3) * 8;
    const unsigned short* src = g + (long)row * ldk + kcol;
    unsigned short* dst = lds + row * 32 + kcol;
    __builtin_amdgcn_global_load_lds((gbl_void_t*)src, (lds_void_t*)dst, 16, 0, 0);
  }
}

__global__ __launch_bounds__(256, 2)
void down_nt_kernel(const unsigned short* __restrict__ Inter,
                    const float* __restrict__ W2,
                    float* __restrict__ Out) {
  __shared__ unsigned short As[128 * 32];
  __shared__ unsigned short Bs[128 * 32];
  const int t = threadIdx.x;
  const int lane = t & 63;
  const int wave = t >> 6;
  const int bm = blockIdx.x & 31;
  const int bn = blockIdx.x >> 5;
  const int wm = (wave >> 1) * 64;
  const int wn = (wave & 1) * 64;
  const unsigned short* gA = Inter + (long)(bm * 128) * FFN;

  f32x4 acc[4][4] = {};
  const int fr = lane & 15;
  const int kg = (lane >> 4) * 8;
  const int p = lane & 15;
  const int h0 = wave * 32 + (lane >> 4) * 8;
  const float* gB = W2 + bn * 128 + h0;

  for (int kt = 0; kt < FFN; kt += 32) {
    __syncthreads();
    stage_tile_128(gA + kt, FFN, As, wave, lane);
    const float* r0p = gB + (long)(kt + 2 * p) * HIDDEN;
    const float* r1p = r0p + HIDDEN;
    const float4 a0 = *reinterpret_cast<const float4*>(r0p);
    const float4 a1 = *reinterpret_cast<const float4*>(r0p + 4);
    const float4 b0 = *reinterpret_cast<const float4*>(r1p);
    const float4 b1 = *reinterpret_cast<const float4*>(r1p + 4);
    unsigned short lo[8], hi[8];
    lo[0] = f2b(a0.x); lo[1] = f2b(a0.y); lo[2] = f2b(a0.z); lo[3] = f2b(a0.w);
    lo[4] = f2b(a1.x); lo[5] = f2b(a1.y); lo[6] = f2b(a1.z); lo[7] = f2b(a1.w);
    hi[0] = f2b(b0.x); hi[1] = f2b(b0.y); hi[2] = f2b(b0.z); hi[3] = f2b(b0.w);
    hi[4] = f2b(b1.x); hi[5] = f2b(b1.y); hi[6] = f2b(b1.z); hi[7] = f2b(b1.w);
#pragma unroll
    for (int j = 0; j < 8; ++j) {
      const unsigned int pack = (unsigned int)lo[j] | ((unsigned int)hi[j] << 16);
      *reinterpret_cast<unsigned int*>(&Bs[(h0 + j) * 32 + 2 * p]) = pack;
    }
    __syncthreads();
    bf16x8 a[4], b[4];
#pragma unroll
    for (int m = 0; m < 4; ++m)
      a[m] = *reinterpret_cast<const bf16x8*>(&As[(wm + m * 16 + fr) * 32 + kg]);
#pragma unroll
    for (int n = 0; n < 4; ++n)
      b[n] = *reinterpret_cast<const bf16x8*>(&Bs[(wn + n * 16 + fr) * 32 + kg]);
#pragma unroll
    for (int m = 0; m < 4; ++m)
#pragma unroll
      for (int n = 0; n < 4; ++n)
        acc[m][n] = MFMA16(a[m], b[n], acc[m][n]);
  }
  const int r0 = (lane >> 4) * 4;
#pragma unroll
  for (int m = 0; m < 4; ++m)
#pragma unroll
    for (int n = 0; n < 4; ++n)
#pragma unroll
      for (int r = 0; r < 4; ++r) {
        const int row = bm * 128 + wm + m * 16 + r0 + r;
        const int col = bn * 128 + wn + n * 16 + fr;
        Out[(long)row * HIDDEN + col] = acc[m][n][r];
      }
}

extern "C" void kernel_launch(void* const* d_in, const int* in_sizes, int n_in,
                              void* d_out, int out_size, void* d_ws, size_t ws_size,
                              hipStream_t stream) {
  const float* x  = (const float*)d_in[0];
  const float* w1 = (const float*)d_in[1];
  const float* v1 = (const float*)d_in[2];
  const float* w2 = (const float*)d_in[3];
  float* out = (float*)d_out;

  // ws layout (bytes): xb 33,554,432 | w1b 117,440,512 | v1b 117,440,512 |
  //                    inter 117,440,512 | w2t 117,440,512  -> 503,316,480 total.
  const size_t REQ_SMALL = 385875968UL;
  const size_t REQ_FULL  = 503316480UL;
  if (ws_size < REQ_SMALL) return;
  const bool full = (ws_size >= REQ_FULL);
  char* ws = (char*)d_ws;
  unsigned short* xb     = (unsigned short*)(ws);
  unsigned short* w1b    = (unsigned short*)(ws + 33554432L);
  unsigned short* v1b    = (unsigned short*)(ws + 150994944L);
  unsigned short* interb = (unsigned short*)(ws + 268435456L);
  unsigned short* w2tb   = (unsigned short*)(ws + 385875968L);

  // half-split: F-rows [0, 8192) = bn64 0..127 ; [8192, 14336) = bn64 128..223
  const long HALF1 = 8192L * HIDDEN;
  const long HALF2 = (long)(FFN - 8192) * HIDDEN;

  hipLaunchKernelGGL(cvt_kernel, dim3(2048), dim3(256), 0, stream, x, xb, (long)TOKENS * HIDDEN);
  hipLaunchKernelGGL(cvt_kernel, dim3(2048), dim3(256), 0, stream, w1, w1b, HALF1);
  hipLaunchKernelGGL(cvt_kernel, dim3(2048), dim3(256), 0, stream, v1, v1b, HALF1);
  hipLaunchKernelGGL(gateup256c_kernel, dim3(16 * 128), dim3(512), 0, stream,
                     xb, w1b, v1b, interb, 0, 16 * 128);
  hipLaunchKernelGGL(cvt_kernel, dim3(2048), dim3(256), 0, stream, w1 + HALF1, w1b + HALF1, HALF2);
  hipLaunchKernelGGL(cvt_kernel, dim3(2048), dim3(256), 0, stream, v1 + HALF1, v1b + HALF1, HALF2);
  hipLaunchKernelGGL(gateup256c_kernel, dim3(16 * 96), dim3(512), 0, stream,
                     xb, w1b, v1b, interb, 128, 16 * 96);

  if (full) {
    hipLaunchKernelGGL(transpose_cvt_kernel, dim3(FFN / 64, HIDDEN / 64), dim3(256), 0, stream, w2, w2tb);
    hipLaunchKernelGGL(down256c_kernel, dim3((TOKENS / 256) * (HIDDEN / 128)), dim3(512), 0, stream,
                       interb, w2tb, out);
  } else {
    hipLaunchKernelGGL(down_nt_kernel, dim3((TOKENS / 128) * (HIDDEN / 128)), dim3(256), 0, stream,
                       interb, w2, out);
  }
}

// Round 19
// 1359.069 us; speedup vs baseline: 1.2016x; 1.2016x over previous
//
#include <hip/hip_runtime.h>
#include <hip/hip_bf16.h>
#include <stdint.h>

// DbrxExpertGLU: down = (silu(x@w1^T) * (x@v1^T)) @ w2
// T=4096, H=4096, F=14336. fp32 in/out; bf16 MFMA compute.
// R19 = revert to R17 (best measured: 1365 us). R18's 2-blocks/CU experiment
// regressed (BK=32 64B-row LDS panels -> 8-way bank conflict on banks {0,16};
// occupancy falsified as the lever). Structure: persistent gateup (grid 256,
// 1 barrier/K-tile, A-dbuf + WV-tribuf 160KB, counted vmcnt(4), 2-tile weight
// lead, temporal cvt/gateup halves) + down256 (A-dbuf + B-tribuf, 1 barrier).
#define TOKENS 4096
#define HIDDEN 4096
#define FFN    14336

typedef __attribute__((ext_vector_type(8))) short bf16x8;
typedef __attribute__((ext_vector_type(4))) float f32x4;
typedef __attribute__((ext_vector_type(8))) unsigned short u16x8;

typedef __attribute__((address_space(3))) void lds_void_t;
typedef const __attribute__((address_space(1))) void gbl_void_t;

static __device__ __forceinline__ unsigned short f2b(float f) {
  union { float f; unsigned int u; } v; v.f = f;
  unsigned int u = v.u;
  return (unsigned short)((u + 0x7FFFu + ((u >> 16) & 1u)) >> 16);  // RNE
}

// ---------------- fp32 -> bf16 convert ----------------
__global__ void cvt_kernel(const float* __restrict__ in, unsigned short* __restrict__ out, long n) {
  long idx = (long)blockIdx.x * blockDim.x + threadIdx.x;
  long stride = (long)gridDim.x * blockDim.x;
  for (long i = idx * 4; i < n; i += stride * 4) {
    const float4 v = *reinterpret_cast<const float4*>(in + i);
    ushort4 o;
    o.x = f2b(v.x); o.y = f2b(v.y); o.z = f2b(v.z); o.w = f2b(v.w);
    *reinterpret_cast<ushort4*>(out + i) = o;
  }
}

// ------- w2 [F][H] fp32 -> w2t [H][F] bf16 -------
__global__ void transpose_cvt_kernel(const float* __restrict__ in, unsigned short* __restrict__ out) {
  __shared__ float tile[64][65];
  const int f0 = blockIdx.x * 64;
  const int h0 = blockIdx.y * 64;
  const int t = threadIdx.x;
  const int rcol = (t & 15) * 4;
  const int rrow = t >> 4;
#pragma unroll
  for (int it = 0; it < 4; ++it) {
    int r = rrow + it * 16;
    const float4 v = *reinterpret_cast<const float4*>(in + (long)(f0 + r) * HIDDEN + h0 + rcol);
    tile[r][rcol] = v.x; tile[r][rcol + 1] = v.y; tile[r][rcol + 2] = v.z; tile[r][rcol + 3] = v.w;
  }
  __syncthreads();
  const int wrow = t >> 2;
  const int wc = (t & 3) * 16;
  u16x8 lo, hi;
#pragma unroll
  for (int j = 0; j < 8; ++j) lo[j] = f2b(tile[wc + j][wrow]);
#pragma unroll
  for (int j = 0; j < 8; ++j) hi[j] = f2b(tile[wc + 8 + j][wrow]);
  u16x8* dst = reinterpret_cast<u16x8*>(out + (long)(h0 + wrow) * FFN + f0 + wc);
  dst[0] = lo; dst[1] = hi;
}

#define MFMA16(a, b, c) __builtin_amdgcn_mfma_f32_16x16x32_bf16((a), (b), (c), 0, 0, 0)
#define SBAR()  __builtin_amdgcn_s_barrier()

static __device__ __forceinline__ int xcd_chunk(int bid, int nwg) {
  return (bid & 7) * (nwg >> 3) + (bid >> 3);
}

// ============ persistent fused gate/up: grid 256, F-tiles j0..j1, 1 barrier/tile ============
// LDS 160KB: A dbuf 2x32KB @0 | WV tribuf 3x32KB (W16K+V16K) @64KB.
__global__ __launch_bounds__(512, 2)
void gateup256p_kernel(const unsigned short* __restrict__ X,
                       const unsigned short* __restrict__ W1,
                       const unsigned short* __restrict__ V1,
                       unsigned short* __restrict__ Inter,
                       int j0, int j1) {
  __shared__ unsigned short sh[81920];  // 160 KB
  const int tid = threadIdx.x, lane = tid & 63, wid = tid >> 6;
  const int wm = wid >> 2, wn = wid & 3;
  const int p = blockIdx.x;           // 0..255, one block per CU
  const int bm = p & 15;              // T-tile (fixed per block)
  const int bnl = p >> 4;             // bn lane 0..15
  const int sr = tid >> 3;
  const int scb = (((tid & 7) ^ (sr & 7)) << 4);
  const int l15 = lane & 15;
  const int cb0 = (((lane >> 4) * 16) ^ ((lane & 7) << 4));
  const int cb1 = ((64 + (lane >> 4) * 16) ^ ((lane & 7) << 4));

  const unsigned short* Ap = X + (long)(bm * 256) * HIDDEN;

  auto LDA8 = [&](bf16x8* a, int bufA, int cb) {
    const char* base = (const char*)sh + bufA * 32768 + wm * 16384 + l15 * 128 + cb;
#pragma unroll
    for (int m = 0; m < 8; ++m) a[m] = *(const bf16x8*)(base + m * 2048);
  };
  auto LDW2 = [&](bf16x8* w, int b3, int cb) {
    const char* base = (const char*)sh + 65536 + b3 * 32768 + (wn * 32 + l15) * 128 + cb;
    w[0] = *(const bf16x8*)(base);
    w[1] = *(const bf16x8*)(base + 2048);
  };
  auto LDV2 = [&](bf16x8* v, int b3, int cb) {
    const char* base = (const char*)sh + 65536 + b3 * 32768 + 16384 + (wn * 32 + l15) * 128 + cb;
    v[0] = *(const bf16x8*)(base);
    v[1] = *(const bf16x8*)(base + 2048);
  };

  for (int j = j0; j < j1; ++j) {
    const int bn = j * 16 + bnl;
    const unsigned short* Wp = W1 + (long)(bn * 128) * HIDDEN;
    const unsigned short* Vp = V1 + (long)(bn * 128) * HIDDEN;

    auto STA = [&](int u, int bufA, int t) {   // A unit u: 64 rows, 8KB
      const unsigned short* src = Ap + (long)(u * 64 + sr) * HIDDEN + t * 64 + (scb >> 1);
      unsigned short* dst = sh + bufA * 16384 + u * 4096 + tid * 8;
      __builtin_amdgcn_global_load_lds((gbl_void_t*)src, (lds_void_t*)dst, 16, 0, 0);
    };
    auto STW = [&](int u, int b3, int t) {
      const unsigned short* src = Wp + (long)(u * 64 + sr) * HIDDEN + t * 64 + (scb >> 1);
      unsigned short* dst = sh + 32768 + b3 * 16384 + u * 4096 + tid * 8;
      __builtin_amdgcn_global_load_lds((gbl_void_t*)src, (lds_void_t*)dst, 16, 0, 0);
    };
    auto STV = [&](int u, int b3, int t) {
      const unsigned short* src = Vp + (long)(u * 64 + sr) * HIDDEN + t * 64 + (scb >> 1);
      unsigned short* dst = sh + 32768 + b3 * 16384 + 8192 + u * 4096 + tid * 8;
      __builtin_amdgcn_global_load_lds((gbl_void_t*)src, (lds_void_t*)dst, 16, 0, 0);
    };

    f32x4 accg[8][2] = {};
    f32x4 accu[8][2] = {};

    // prologue (ledger order): WV(0)->slot0; A(0)->buf0; WV(1)->slot1
    STW(0, 0, 0); STW(1, 0, 0); STV(0, 0, 0); STV(1, 0, 0);
    STA(0, 0, 0); STA(1, 0, 0); STA(2, 0, 0); STA(3, 0, 0);
    STW(0, 1, 1); STW(1, 1, 1); STV(0, 1, 1); STV(1, 1, 1);

    bf16x8 a0[8], w0[2], v0[2];   // kk0 fragment set
    bf16x8 a1[8], w1[2], v1[2];   // kk1 fragment set
    const int NT = HIDDEN / 64;  // 64
    for (int t = 0; t < NT; ++t) {
      const int curA = t & 1, nxtA = curA ^ 1;
      const int b3 = t % 3, b3w = (t + 2) % 3;
      // own ds_reads of tile t-1 complete before crossing barrier (WAR safety)
      asm volatile("s_waitcnt lgkmcnt(0)" ::: "memory");
      // gate: keep only newest 4 (WV(t+1)); drains A(t), WV(t)
      if (t + 1 < NT) { asm volatile("s_waitcnt vmcnt(4)" ::: "memory"); }
      else            { asm volatile("s_waitcnt vmcnt(0)" ::: "memory"); }
      SBAR();  // single barrier per tile
      // post-barrier staging (ledger order): A(t+1) FIRST, then WV(t+2)
      if (t + 1 < NT) { STA(0, nxtA, t + 1); STA(1, nxtA, t + 1);
                        STA(2, nxtA, t + 1); STA(3, nxtA, t + 1); }
      if (t + 2 < NT) { STW(0, b3w, t + 2); STW(1, b3w, t + 2);
                        STV(0, b3w, t + 2); STV(1, b3w, t + 2); }
      // hoist ALL tile reads up front (both ksteps, disjoint reg sets)
      LDA8(a0, curA, cb0); LDW2(w0, b3, cb0); LDV2(v0, b3, cb0);
      LDA8(a1, curA, cb1); LDW2(w1, b3, cb1); LDV2(v1, b3, cb1);
      // kk0 MFMAs (compiler waits only kk0 reads; kk1 drains underneath)
      __builtin_amdgcn_s_setprio(1);
#pragma unroll
      for (int m = 0; m < 8; ++m) {
        accg[m][0] = MFMA16(a0[m], w0[0], accg[m][0]);
        accg[m][1] = MFMA16(a0[m], w0[1], accg[m][1]);
      }
#pragma unroll
      for (int m = 0; m < 8; ++m) {
        accu[m][0] = MFMA16(a0[m], v0[0], accu[m][0]);
        accu[m][1] = MFMA16(a0[m], v0[1], accu[m][1]);
      }
      // kk1 MFMAs
#pragma unroll
      for (int m = 0; m < 8; ++m) {
        accg[m][0] = MFMA16(a1[m], w1[0], accg[m][0]);
        accg[m][1] = MFMA16(a1[m], w1[1], accg[m][1]);
      }
#pragma unroll
      for (int m = 0; m < 8; ++m) {
        accu[m][0] = MFMA16(a1[m], v1[0], accu[m][0]);
        accu[m][1] = MFMA16(a1[m], v1[1], accu[m][1]);
      }
      __builtin_amdgcn_s_setprio(0);
    }
    // epilogue: silu(g)*u -> bf16. C/D map: col=lane&15, row=(lane>>4)*4+r (m89)
    const int r0 = (lane >> 4) * 4;
#pragma unroll
    for (int m = 0; m < 8; ++m)
#pragma unroll
      for (int n = 0; n < 2; ++n)
#pragma unroll
        for (int r = 0; r < 4; ++r) {
          const float g = accg[m][n][r];
          const float u = accu[m][n][r];
          const float s = g / (1.0f + __expf(-g));
          const int row = bm * 256 + wm * 128 + m * 16 + r0 + r;
          const int col = bn * 128 + wn * 32 + n * 16 + l15;
          Inter[(long)row * FFN + col] = f2b(s * u);
        }
    // drain epilogue stores so the next group's vmcnt ledger starts clean
    asm volatile("s_waitcnt vmcnt(0)" ::: "memory");
  }
}

// ============ down GEMM-BT: 256x256, BK=64, 8 waves, 1 barrier/tile ============
// LDS 160KB: A dbuf 2x32KB @0 | B tribuf 3x32KB @64KB.
__global__ __launch_bounds__(512, 2)
void down256_kernel(const unsigned short* __restrict__ Inter,
                    const unsigned short* __restrict__ W2t,
                    float* __restrict__ Out) {
  __shared__ unsigned short sh[81920];  // 160 KB
  const int tid = threadIdx.x, lane = tid & 63, wid = tid >> 6;
  const int wm = wid >> 2, wn = wid & 3;
  const int swz = xcd_chunk(blockIdx.x, (TOKENS / 256) * (HIDDEN / 256));  // 256
  const int bm = swz & 15;
  const int bn = swz >> 4;
  const int sr = tid >> 3;
  const int scb = (((tid & 7) ^ (sr & 7)) << 4);
  const int l15 = lane & 15;
  const int cb0 = (((lane >> 4) * 16) ^ ((lane & 7) << 4));
  const int cb1 = ((64 + (lane >> 4) * 16) ^ ((lane & 7) << 4));

  const unsigned short* Ap = Inter + (long)(bm * 256) * FFN;
  const unsigned short* Bp = W2t + (long)(bn * 256) * FFN;

  f32x4 acc[8][4] = {};

  auto STA = [&](int h, int bufA, int t) {   // A half h: 128 rows, 2 gloads
    const unsigned short* src = Ap + (long)(h * 128 + sr) * FFN + t * 64 + (scb >> 1);
    unsigned short* dst = sh + bufA * 16384 + h * 8192 + tid * 8;
    __builtin_amdgcn_global_load_lds((gbl_void_t*)src, (lds_void_t*)dst, 16, 0, 0);
    __builtin_amdgcn_global_load_lds((gbl_void_t*)(src + 64L * FFN), (lds_void_t*)(dst + 4096), 16, 0, 0);
  };
  auto STB = [&](int h, int s3, int t) {     // B half h into tri-slot s3
    const unsigned short* src = Bp + (long)(h * 128 + sr) * FFN + t * 64 + (scb >> 1);
    unsigned short* dst = sh + 32768 + s3 * 16384 + h * 8192 + tid * 8;
    __builtin_amdgcn_global_load_lds((gbl_void_t*)src, (lds_void_t*)dst, 16, 0, 0);
    __builtin_amdgcn_global_load_lds((gbl_void_t*)(src + 64L * FFN), (lds_void_t*)(dst + 4096), 16, 0, 0);
  };
  auto LDA8 = [&](bf16x8* a, int bufA, int cb) {
    const char* base = (const char*)sh + bufA * 32768 + wm * 16384 + l15 * 128 + cb;
#pragma unroll
    for (int m = 0; m < 8; ++m) a[m] = *(const bf16x8*)(base + m * 2048);
  };
  auto LDB4 = [&](bf16x8* b, int s3, int cb) {
    const char* base = (const char*)sh + 65536 + s3 * 32768 + (wn >> 1) * 16384 +
                       ((wn & 1) * 64 + l15) * 128 + cb;
#pragma unroll
    for (int n = 0; n < 4; ++n) b[n] = *(const bf16x8*)(base + n * 2048);
  };

  // prologue (ledger order): B(0)->s0; A(0)->buf0; B(1)->s1
  STB(0, 0, 0); STB(1, 0, 0);
  STA(0, 0, 0); STA(1, 0, 0);
  STB(0, 1, 1); STB(1, 1, 1);

  bf16x8 a0[8], b0[4];   // kk0
  bf16x8 a1[8], b1[4];   // kk1
  const int NT = FFN / 64;  // 224
  for (int t = 0; t < NT; ++t) {
    const int curA = t & 1, nxtA = curA ^ 1;
    const int b3 = t % 3, b3w = (t + 2) % 3;
    asm volatile("s_waitcnt lgkmcnt(0)" ::: "memory");
    if (t + 1 < NT) { asm volatile("s_waitcnt vmcnt(4)" ::: "memory"); }
    else            { asm volatile("s_waitcnt vmcnt(0)" ::: "memory"); }
    SBAR();
    if (t + 1 < NT) { STA(0, nxtA, t + 1); STA(1, nxtA, t + 1); }
    if (t + 2 < NT) { STB(0, b3w, t + 2); STB(1, b3w, t + 2); }
    // hoist all reads (both ksteps)
    LDA8(a0, curA, cb0); LDB4(b0, b3, cb0);
    LDA8(a1, curA, cb1); LDB4(b1, b3, cb1);
    __builtin_amdgcn_s_setprio(1);
#pragma unroll
    for (int m = 0; m < 8; ++m) {
      acc[m][0] = MFMA16(a0[m], b0[0], acc[m][0]);
      acc[m][1] = MFMA16(a0[m], b0[1], acc[m][1]);
    }
#pragma unroll
    for (int m = 0; m < 8; ++m) {
      acc[m][2] = MFMA16(a0[m], b0[2], acc[m][2]);
      acc[m][3] = MFMA16(a0[m], b0[3], acc[m][3]);
    }
#pragma unroll
    for (int m = 0; m < 8; ++m) {
      acc[m][0] = MFMA16(a1[m], b1[0], acc[m][0]);
      acc[m][1] = MFMA16(a1[m], b1[1], acc[m][1]);
    }
#pragma unroll
    for (int m = 0; m < 8; ++m) {
      acc[m][2] = MFMA16(a1[m], b1[2], acc[m][2]);
      acc[m][3] = MFMA16(a1[m], b1[3], acc[m][3]);
    }
    __builtin_amdgcn_s_setprio(0);
  }
  const int r0 = (lane >> 4) * 4;
#pragma unroll
  for (int m = 0; m < 8; ++m)
#pragma unroll
    for (int n = 0; n < 4; ++n)
#pragma unroll
      for (int r = 0; r < 4; ++r) {
        const int row = bm * 256 + wm * 128 + m * 16 + r0 + r;
        const int col = bn * 256 + wn * 64 + n * 16 + l15;
        Out[(long)row * HIDDEN + col] = acc[m][n][r];
      }
}

// ---- fallback down (round-2 verified) when ws lacks w2t space ----
__device__ __forceinline__ void stage_tile_128(const unsigned short* __restrict__ g, long ldk,
                                               unsigned short* lds, int wave, int lane) {
#pragma unroll
  for (int it = 0; it < 2; ++it) {
    const int row = (it * 4 + wave) * 16 + (lane >> 2);
    const int kcol = (lane & 3) * 8;
    const unsigned short* src = g + (long)row * ldk + kcol;
    unsigned short* dst = lds + row * 32 + kcol;
    __builtin_amdgcn_global_load_lds((gbl_void_t*)src, (lds_void_t*)dst, 16, 0, 0);
  }
}

__global__ __launch_bounds__(256, 2)
void down_nt_kernel(const unsigned short* __restrict__ Inter,
                    const float* __restrict__ W2,
                    float* __restrict__ Out) {
  __shared__ unsigned short As[128 * 32];
  __shared__ unsigned short Bs[128 * 32];
  const int t = threadIdx.x;
  const int lane = t & 63;
  const int wave = t >> 6;
  const int bm = blockIdx.x & 31;
  const int bn = blockIdx.x >> 5;
  const int wm = (wave >> 1) * 64;
  const int wn = (wave & 1) * 64;
  const unsigned short* gA = Inter + (long)(bm * 128) * FFN;

  f32x4 acc[4][4] = {};
  const int fr = lane & 15;
  const int kg = (lane >> 4) * 8;
  const int p = lane & 15;
  const int h0 = wave * 32 + (lane >> 4) * 8;
  const float* gB = W2 + bn * 128 + h0;

  for (int kt = 0; kt < FFN; kt += 32) {
    __syncthreads();
    stage_tile_128(gA + kt, FFN, As, wave, lane);
    const float* r0p = gB + (long)(kt + 2 * p) * HIDDEN;
    const float* r1p = r0p + HIDDEN;
    const float4 a0 = *reinterpret_cast<const float4*>(r0p);
    const float4 a1 = *reinterpret_cast<const float4*>(r0p + 4);
    const float4 b0 = *reinterpret_cast<const float4*>(r1p);
    const float4 b1 = *reinterpret_cast<const float4*>(r1p + 4);
    unsigned short lo[8], hi[8];
    lo[0] = f2b(a0.x); lo[1] = f2b(a0.y); lo[2] = f2b(a0.z); lo[3] = f2b(a0.w);
    lo[4] = f2b(a1.x); lo[5] = f2b(a1.y); lo[6] = f2b(a1.z); lo[7] = f2b(a1.w);
    hi[0] = f2b(b0.x); hi[1] = f2b(b0.y); hi[2] = f2b(b0.z); hi[3] = f2b(b0.w);
    hi[4] = f2b(b1.x); hi[5] = f2b(b1.y); hi[6] = f2b(b1.z); hi[7] = f2b(b1.w);
#pragma unroll
    for (int j = 0; j < 8; ++j) {
      const unsigned int pack = (unsigned int)lo[j] | ((unsigned int)hi[j] << 16);
      *reinterpret_cast<unsigned int*>(&Bs[(h0 + j) * 32 + 2 * p]) = pack;
    }
    __syncthreads();
    bf16x8 a[4], b[4];
#pragma unroll
    for (int m = 0; m < 4; ++m)
      a[m] = *reinterpret_cast<const bf16x8*>(&As[(wm + m * 16 + fr) * 32 + kg]);
#pragma unroll
    for (int n = 0; n < 4; ++n)
      b[n] = *reinterpret_cast<const bf16x8*>(&Bs[(wn + n * 16 + fr) * 32 + kg]);
#pragma unroll
    for (int m = 0; m < 4; ++m)
#pragma unroll
      for (int n = 0; n < 4; ++n)
        acc[m][n] = MFMA16(a[m], b[n], acc[m][n]);
  }
  const int r0 = (lane >> 4) * 4;
#pragma unroll
  for (int m = 0; m < 4; ++m)
#pragma unroll
    for (int n = 0; n < 4; ++n)
#pragma unroll
      for (int r = 0; r < 4; ++r) {
        const int row = bm * 128 + wm + m * 16 + r0 + r;
        const int col = bn * 128 + wn + n * 16 + fr;
        Out[(long)row * HIDDEN + col] = acc[m][n][r];
      }
}

extern "C" void kernel_launch(void* const* d_in, const int* in_sizes, int n_in,
                              void* d_out, int out_size, void* d_ws, size_t ws_size,
                              hipStream_t stream) {
  const float* x  = (const float*)d_in[0];
  const float* w1 = (const float*)d_in[1];
  const float* v1 = (const float*)d_in[2];
  const float* w2 = (const float*)d_in[3];
  float* out = (float*)d_out;

  // ws layout (bytes): xb 33,554,432 | w1b 117,440,512 | v1b 117,440,512 |
  //                    inter 117,440,512 | w2t 117,440,512  -> 503,316,480 total.
  const size_t REQ_SMALL = 385875968UL;
  const size_t REQ_FULL  = 503316480UL;
  if (ws_size < REQ_SMALL) return;
  const bool full = (ws_size >= REQ_FULL);
  char* ws = (char*)d_ws;
  unsigned short* xb     = (unsigned short*)(ws);
  unsigned short* w1b    = (unsigned short*)(ws + 33554432L);
  unsigned short* v1b    = (unsigned short*)(ws + 150994944L);
  unsigned short* interb = (unsigned short*)(ws + 268435456L);
  unsigned short* w2tb   = (unsigned short*)(ws + 385875968L);

  // half-split: F-rows [0, 8192) = j 0..3 ; F-rows [8192, 14336) = j 4..6
  const long HALF1 = 8192L * HIDDEN;
  const long HALF2 = (long)(FFN - 8192) * HIDDEN;

  hipLaunchKernelGGL(cvt_kernel, dim3(2048), dim3(256), 0, stream, x, xb, (long)TOKENS * HIDDEN);
  hipLaunchKernelGGL(cvt_kernel, dim3(2048), dim3(256), 0, stream, w1, w1b, HALF1);
  hipLaunchKernelGGL(cvt_kernel, dim3(2048), dim3(256), 0, stream, v1, v1b, HALF1);
  hipLaunchKernelGGL(gateup256p_kernel, dim3(256), dim3(512), 0, stream,
                     xb, w1b, v1b, interb, 0, 4);
  hipLaunchKernelGGL(cvt_kernel, dim3(2048), dim3(256), 0, stream, w1 + HALF1, w1b + HALF1, HALF2);
  hipLaunchKernelGGL(cvt_kernel, dim3(2048), dim3(256), 0, stream, v1 + HALF1, v1b + HALF1, HALF2);
  hipLaunchKernelGGL(gateup256p_kernel, dim3(256), dim3(512), 0, stream,
                     xb, w1b, v1b, interb, 4, 7);

  if (full) {
    hipLaunchKernelGGL(transpose_cvt_kernel, dim3(FFN / 64, HIDDEN / 64), dim3(256), 0, stream, w2, w2tb);
    hipLaunchKernelGGL(down256_kernel, dim3((TOKENS / 256) * (HIDDEN / 256)), dim3(512), 0, stream,
                       interb, w2tb, out);
  } else {
    hipLaunchKernelGGL(down_nt_kernel, dim3((TOKENS / 128) * (HIDDEN / 128)), dim3(256), 0, stream,
                       interb, w2, out);
  }
}